// Round 1
// baseline (800.291 us; speedup 1.0000x reference)
//
#include <hip/hip_runtime.h>

// DepConv3D: depth-gated 3x3 conv, B=4, iC=16, oC=32, H=W=512, pad=1, stride=1.
// Reference semantics: for tap (kh,kw), diff = depth[nbr] - depth[center];
//   diff == -1 -> weight slice kd=0; diff == 0 -> kd=1; anything else -> zero.
//   (kd=2 is unreachable: diff>=1 maps to the appended zero slice.)
// weight flat layout: [oc][ic][kd][kh][kw] -> oc*432 + ic*27 + kd*9 + kh*3+kw.

#define IC 16
#define OC 32
#define Hh 512
#define Ww 512
#define HW (Hh * Ww)

__global__ __launch_bounds__(256) void depconv_fp32(
    const float* __restrict__ feat,   // (4,16,512,512)
    const int*   __restrict__ depth,  // (4,512,512)
    const float* __restrict__ wgt,    // (32,16,3,3,3)
    float*       __restrict__ out)    // (4,32,512,512)
{
    const int p  = blockIdx.x * 256 + threadIdx.x;  // pixel id over 4*512*512
    const int b  = p >> 18;
    const int hw = p & (HW - 1);
    const int h  = hw >> 9;
    const int w  = hw & (Ww - 1);

    const int dc = depth[(b << 18) + hw];
    const float* fb = feat + (size_t)b * (IC * HW);

    float acc[OC];
#pragma unroll
    for (int i = 0; i < OC; ++i) acc[i] = 0.f;

#pragma unroll
    for (int t = 0; t < 9; ++t) {
        const int kh = t / 3, kw = t % 3;
        const int y = h + kh - 1;
        const int x = w + kw - 1;
        const bool inb = ((unsigned)y < (unsigned)Hh) && ((unsigned)x < (unsigned)Ww);
        const int nof = y * Ww + x;

        int dn = 0;
        if (inb) dn = depth[(b << 18) + nof];
        const int diff = dn - dc;

        // center tap: diff is always 0 -> only kd=1 slice fires (compile-time split)
        const bool m0 = (t != 4) && inb && (diff == -1);
        const bool m1 = inb && (diff == 0);

        const float* wp = wgt + t;  // add oc*432 + ic*27 (+9 for kd=1)

#pragma unroll 2
        for (int ic = 0; ic < IC; ++ic) {
            float f = 0.f;
            if (inb) f = fb[ic * HW + nof];
            const float f1 = m1 ? f : 0.f;
            if (t == 4) {
                // center: only kd=1
#pragma unroll
                for (int oc = 0; oc < OC; ++oc) {
                    acc[oc] += wp[oc * 432 + ic * 27 + 9] * f1;
                }
            } else {
                const float f0 = m0 ? f : 0.f;
#pragma unroll
                for (int oc = 0; oc < OC; ++oc) {
                    const float w0 = wp[oc * 432 + ic * 27];      // kd=0 (diff=-1)
                    const float w1 = wp[oc * 432 + ic * 27 + 9];  // kd=1 (diff=0)
                    acc[oc] += w0 * f0 + w1 * f1;
                }
            }
        }
    }

    float* op = out + ((size_t)b * OC) * HW + hw;
#pragma unroll
    for (int oc = 0; oc < OC; ++oc) {
        op[(size_t)oc * HW] = acc[oc];
    }
}

extern "C" void kernel_launch(void* const* d_in, const int* in_sizes, int n_in,
                              void* d_out, int out_size, void* d_ws, size_t ws_size,
                              hipStream_t stream) {
    const float* feat  = (const float*)d_in[0];
    const int*   depth = (const int*)d_in[1];
    const float* wgt   = (const float*)d_in[2];
    float* out = (float*)d_out;

    const int total = 4 * HW;           // 1,048,576 pixels
    dim3 grid(total / 256), block(256);
    depconv_fp32<<<grid, block, 0, stream>>>(feat, depth, wgt, out);
}

// Round 2
// 273.494 us; speedup vs baseline: 2.9262x; 2.9262x over previous
//
#include <hip/hip_runtime.h>

// DepConv3D via bf16 MFMA: out[b,oc,h,w] = sum_{t,ic,kd} W[oc,ic,kd,t] * Fgated[t,ic,kd,pixel]
//   diff = depth[nbr]-depth[center]; kd=0 iff diff==-1, kd=1 iff diff==0, else zero.
//   kd=2 slice is unreachable (reference maps diff>=1 to the appended zero slice).
// K = 9*16*2 = 288, decomposed k = t*32 + ic*2 + kd; K-chunk c (32 wide) == tap t.
// A (weights, M=32 oc) prepacked into per-lane MFMA fragments in d_ws by prep kernel.
// B (gated features) built per 64-pixel tile in LDS, fp32->bf16 RNE.

#define IC 16
#define OC 32
#define Hh 512
#define Ww 512
#define HW (Hh * Ww)
#define KTOT 288
#define KSTRIDE 296   // bf16 per pixel row in LDS (592 B = 148 words; 2-way banks only)

typedef __attribute__((ext_vector_type(8))) short short8;     // 8 bf16 = 4 VGPRs
typedef __attribute__((ext_vector_type(4))) float float4v;    // MFMA accum
typedef __attribute__((ext_vector_type(4))) unsigned int uint4v;

__device__ __forceinline__ unsigned short f2bf(float x) {
    unsigned u = __float_as_uint(x);
    unsigned r = u + 0x7FFFu + ((u >> 16) & 1u);   // round-to-nearest-even
    return (unsigned short)(r >> 16);
}

// ---- prepass: fp32 weights (32,16,3,3,3) -> bf16 A-fragments in ws ----
// ws16[e], e = c*1024 + mt*512 + lane*8 + j  (c=chunk/tap, mt=oc-tile, j in lane frag)
//   oc = mt*16 + (lane&15); kk = (lane>>4)*8 + j; ic = kk>>1; kd = kk&1; t = c.
__global__ void prep_weights(const float* __restrict__ wgt,
                             unsigned short* __restrict__ wsA) {
    int e = blockIdx.x * 256 + threadIdx.x;
    if (e >= 9 * 2 * 64 * 8) return;
    int j    = e & 7;
    int lane = (e >> 3) & 63;
    int mt   = (e >> 9) & 1;
    int c    = e >> 10;
    int oc = mt * 16 + (lane & 15);
    int kk = ((lane >> 4) << 3) + j;
    int ic = kk >> 1;
    int kd = kk & 1;
    wsA[e] = f2bf(wgt[oc * 432 + ic * 27 + kd * 9 + c]);
}

// ---- main kernel: 256 threads, 256 pixels per block (4 x 64-pixel subtiles) ----
__global__ __launch_bounds__(256, 2) void depconv_mfma(
    const float* __restrict__ feat,   // (4,16,512,512)
    const int*   __restrict__ depth,  // (4,512,512)
    const unsigned short* __restrict__ wsA,
    float*       __restrict__ out)    // (4,32,512,512)
{
    __shared__ unsigned short Blds[64 * KSTRIDE];   // 37,888 B

    const int tid  = threadIdx.x;
    const int lane = tid & 63;
    const int wv   = tid >> 6;      // wave 0..3

    // A fragments: 9 chunks x 2 oc-tiles, per-lane 16B coalesced loads (L2-resident)
    short8 afrag[9][2];
    {
        const short8* ap = (const short8*)wsA;
#pragma unroll
        for (int c = 0; c < 9; ++c) {
            afrag[c][0] = ap[(c * 2 + 0) * 64 + lane];
            afrag[c][1] = ap[(c * 2 + 1) * 64 + lane];
        }
    }

    const int P0    = blockIdx.x * 256;   // never crosses batch/row-pair boundaries
    const int b     = P0 >> 18;
    const int hw0   = P0 & (HW - 1);
    const int h     = hw0 >> 9;
    const int wbase = hw0 & (Ww - 1);     // 0 or 256

    const int p   = tid & 63;   // build-phase pixel within subtile
    const int icg = tid >> 6;   // build-phase ic group (4 ic each)

    for (int it = 0; it < 4; ++it) {
        const int w0 = wbase + it * 64;
        const int w  = w0 + p;
        const int dc = depth[(b << 18) + h * Ww + w];

        // ---- build gated B in LDS: B[pixel][k], k = t*32 + ic*2 + kd ----
#pragma unroll
        for (int t = 0; t < 9; ++t) {
            const int kh = t / 3, kw = t % 3;
            const int y = h + kh - 1;
            const int x = w + kw - 1;
            const bool inb = ((unsigned)y < (unsigned)Hh) && ((unsigned)x < (unsigned)Ww);
            unsigned pk0 = 0, pk1 = 0, pk2 = 0, pk3 = 0;
            if (inb) {
                const int dn = depth[(b << 18) + y * Ww + x];
                const int diff = dn - dc;
                const bool m0 = (diff == -1);
                const bool m1 = (diff == 0);
                const float* fp = feat + (size_t)(b * IC + icg * 4) * HW + y * Ww + x;
                float f0 = fp[0 * HW], f1 = fp[1 * HW], f2 = fp[2 * HW], f3 = fp[3 * HW];
                pk0 = (unsigned)f2bf(m0 ? f0 : 0.f) | ((unsigned)f2bf(m1 ? f0 : 0.f) << 16);
                pk1 = (unsigned)f2bf(m0 ? f1 : 0.f) | ((unsigned)f2bf(m1 ? f1 : 0.f) << 16);
                pk2 = (unsigned)f2bf(m0 ? f2 : 0.f) | ((unsigned)f2bf(m1 ? f2 : 0.f) << 16);
                pk3 = (unsigned)f2bf(m0 ? f3 : 0.f) | ((unsigned)f2bf(m1 ? f3 : 0.f) << 16);
            }
            // 16B aligned: p*592 + t*64 + icg*16
            uint4v* dst = (uint4v*)((char*)Blds + p * (KSTRIDE * 2) + t * 64 + icg * 16);
            *dst = (uint4v){pk0, pk1, pk2, pk3};
        }
        __syncthreads();

        // ---- MFMA phase: wave wv owns pixels wv*16 + (lane&15) ----
        const int pn   = (wv << 4) + (lane & 15);
        const int koff = (lane >> 4) * 16;   // byte offset of k-pack within 64B chunk
        const char* bbase = (const char*)Blds + pn * (KSTRIDE * 2) + koff;
        float4v acc0 = {0.f, 0.f, 0.f, 0.f};
        float4v acc1 = {0.f, 0.f, 0.f, 0.f};
#pragma unroll
        for (int c = 0; c < 9; ++c) {
            short8 bfrag = *(const short8*)(bbase + c * 64);
            acc0 = __builtin_amdgcn_mfma_f32_16x16x32_bf16(afrag[c][0], bfrag, acc0, 0, 0, 0);
            acc1 = __builtin_amdgcn_mfma_f32_16x16x32_bf16(afrag[c][1], bfrag, acc1, 0, 0, 0);
        }

        // ---- write: D col=lane&15 -> pixel, row=(lane>>4)*4+r -> oc ----
        const int wout  = w0 + pn;
        const int rbase = (lane >> 4) * 4;
        float* op = out + ((size_t)(b * OC) << 18) + h * Ww + wout;
#pragma unroll
        for (int r = 0; r < 4; ++r) {
            op[(size_t)(rbase + r) * HW]      = acc0[r];
            op[(size_t)(16 + rbase + r) * HW] = acc1[r];
        }
        __syncthreads();   // protect Blds before next subtile rebuild
    }
}

extern "C" void kernel_launch(void* const* d_in, const int* in_sizes, int n_in,
                              void* d_out, int out_size, void* d_ws, size_t ws_size,
                              hipStream_t stream) {
    const float* feat  = (const float*)d_in[0];
    const int*   depth = (const int*)d_in[1];
    const float* wgt   = (const float*)d_in[2];
    float* out = (float*)d_out;
    unsigned short* wsA = (unsigned short*)d_ws;   // 18,432 B used

    prep_weights<<<36, 256, 0, stream>>>(wgt, wsA);

    const int total = 4 * HW;                      // 1,048,576 pixels
    depconv_mfma<<<total / 256, 256, 0, stream>>>(feat, depth, wsA, out);
}